// Round 11
// baseline (665.033 us; speedup 1.0000x reference)
//
#include <hip/hip_runtime.h>
#include <hip/hip_bf16.h>
#include <stdint.h>

#define B_  256
#define T_  128
#define E_  256
#define H_  512
#define G4  2048
#define U1_ 256
#define U2_ 64

#define HB_STEP   (16 * 16 * 64 * 8)   // shorts per h step-buffer (256 KB)
#define XF_STEP   (16 * 8 * 64 * 8)    // shorts per x step (128 KB)
#define SGN 0x8000800080008000ULL

typedef __attribute__((ext_vector_type(8))) short bf16x8;
typedef __attribute__((ext_vector_type(4))) float f32x4;
typedef __attribute__((ext_vector_type(2))) unsigned long long ullx2;
typedef unsigned long long ull;

static __device__ __forceinline__ unsigned short f2bf(float f) {
    unsigned u = __float_as_uint(f);
    unsigned r = (u + 0x7FFFu + ((u >> 16) & 1u)) >> 16;   // RNE
    return (unsigned short)r;
}
static __device__ __forceinline__ ull ald(const ull* p) {
    return __hip_atomic_load(p, __ATOMIC_RELAXED, __HIP_MEMORY_SCOPE_AGENT);
}
static __device__ __forceinline__ void ast(ull* p, ull v) {
    __hip_atomic_store(p, v, __ATOMIC_RELAXED, __HIP_MEMORY_SCOPE_AGENT);
}

// ---------- A0: pack U,W (f32 row-major) into bf16 MFMA A-frag layout ----------
__global__ __launch_bounds__(256) void k_prep(const float* __restrict__ U,
                                              const float* __restrict__ W,
                                              short* __restrict__ wpk) {
    __shared__ float ld[32][64];
    const int bj = blockIdx.x;          // 0..31: (gate, 64-wide j window)
    const int g  = bj >> 3;
    const int l0 = (bj & 7) * 64;
    const int t  = threadIdx.x;
    const int p   = t >> 4;             // 0..15 -> (hs_local, blk)
    const int hsl = p >> 1, blk = p & 1;
    const int ci  = t & 3;
    const int g4w = (t >> 2) & 3;
    const int hs  = (l0 >> 3) + hsl;
    const int c16 = g * 4 + ci;
    const int jloc = hsl * 8 + blk * 4 + ci;
    for (int kc = 0; kc < 24; ++kc) {
        const float* src = (kc < 16) ? (U + (long)(kc * 32) * G4)
                                     : (W + (long)((kc - 16) * 32) * G4);
        #pragma unroll
        for (int r = 0; r < 8; ++r) {
            int row = r * 4 + (t >> 6);
            ld[row][t & 63] = src[(long)row * G4 + g * 512 + l0 + (t & 63)];
        }
        __syncthreads();
        bf16x8 o;
        #pragma unroll
        for (int e = 0; e < 8; ++e) o[e] = (short)f2bf(ld[g4w * 8 + e][jloc]);
        *(bf16x8*)(wpk + (((long)(hs * 2 + blk) * 24 + kc) * 64 + (g4w * 16 + c16)) * 8) = o;
        __syncthreads();
    }
}

// ---------- A1: gather embeddings -> x in MFMA B-frag layout (bf16) ----------
__global__ __launch_bounds__(256) void k_gather(const int* __restrict__ inp,
                                                const float* __restrict__ emb,
                                                short* __restrict__ xfrag) {
    const int tid  = threadIdx.x;
    const int wv   = tid >> 6;
    const int lane = tid & 63;
    const int c16  = lane & 15;
    const int g4   = lane >> 4;
    for (int it = 0; it < 16; ++it) {
        int task  = (it * 256 + blockIdx.x) * 4 + wv;   // t*128 + btile*8 + kc
        int kc    = task & 7;
        int btile = (task >> 3) & 15;
        int t     = task >> 7;
        int b     = btile * 16 + c16;
        int idx   = inp[b * T_ + t];
        const float* src = emb + (long)idx * E_ + kc * 32 + g4 * 8;
        float4 v0 = *(const float4*)src;
        float4 v1 = *(const float4*)(src + 4);
        bf16x8 o;
        o[0]=(short)f2bf(v0.x); o[1]=(short)f2bf(v0.y); o[2]=(short)f2bf(v0.z); o[3]=(short)f2bf(v0.w);
        o[4]=(short)f2bf(v1.x); o[5]=(short)f2bf(v1.y); o[6]=(short)f2bf(v1.z); o[7]=(short)f2bf(v1.w);
        *(bf16x8*)(xfrag + ((long)((t * 16 + btile) * 8 + kc) * 64 + lane) * 8) = o;
    }
}

// ---------------- B: persistent recurrent kernel, pure dataflow ----------------
// r7-proven comms (relaxed agent 8B stores/loads, data-as-flag on bf16 sign
// bits, write-once 0xAA-poisoned T-deep buffer), new topology: 128 WGs x 512
// threads. WG = (bt, hh): 8 waves share batch-tile bt; wave wv owns hidden
// slice hs = hh*8+wv. Pipeline bt = 8 WGs (vs 16): the WG's 8 waves produce
// the WG's TWO frags entirely (frag kcw = hh*2+(wv>>2), slot (wv&3)*16+c16),
// so each WG polls 14 frags from only 7 producers; both self frags arrive via
// LDS with zero L3 traffic. Poll traffic/sweep halves; straggler fan-in 7.
__global__ __launch_bounds__(512, 1) void k_lstm(
    const float* __restrict__ bias,   // [G4]
    const short* __restrict__ wpk,    // packed A-frags
    const short* __restrict__ xfrag,  // [T_][16][8][64][8] bf16
    short* hfrag,                     // [T_-1][16][16][64][8] bf16, poisoned
    float* hfin)                      // [B_][H_] f32
{
    __shared__ short lds[2][16][64][8];   // 2 x 16 KB h-frag buffers
    const int tid  = threadIdx.x;
    const int wid  = blockIdx.x;      // 0..127
    const int bt   = wid >> 3;        // batch tile 0..15 (16 rows)
    const int hh   = wid & 7;         // hidden group; WG owns frags 2hh,2hh+1
    const int lane = tid & 63;
    const int wv   = tid >> 6;        // wave 0..7
    const int hs   = hh * 8 + wv;     // this wave's hidden slice (8 units)
    const int c16  = lane & 15;
    const int g4   = lane >> 4;
    const int kcw  = hh * 2 + (wv >> 2);   // frag this wave publishes into
    const bool pollme = (wv != hh);   // wave hh's 2 poll frags are both self

    // Persistent A-frags, coalesced load from wpk (2 j-blocks x (16 U + 8 W))
    bf16x8 a_u[2][16], a_w[2][8];
    #pragma unroll
    for (int blk = 0; blk < 2; ++blk) {
        #pragma unroll
        for (int kc = 0; kc < 16; ++kc)
            a_u[blk][kc] = *(const bf16x8*)(wpk + (((long)(hs*2+blk)*24 + kc)*64 + lane)*8);
        #pragma unroll
        for (int kc = 0; kc < 8; ++kc)
            a_w[blk][kc] = *(const bf16x8*)(wpk + (((long)(hs*2+blk)*24 + 16 + kc)*64 + lane)*8);
    }
    float b0[4], b1[4];
    #pragma unroll
    for (int q = 0; q < 4; ++q) {
        b0[q] = bias[g4 * H_ + hs * 8 + q];
        b1[q] = bias[g4 * H_ + hs * 8 + 4 + q];
    }
    float cst[8];
    #pragma unroll
    for (int i = 0; i < 8; ++i) cst[i] = 0.f;

    // publish slot: frag (bt, kcw), lane slot (wv&3)*16 + c16
    ull* const pub0 = (ull*)hfrag +
        (((long)bt * 16 + kcw) * 64 + (wv & 3) * 16 + c16) * 2;

    for (int t = 0; t < T_; ++t) {
        const int cb = t & 1;
        // 1) issue polls for this wave's 2 assigned frags (kc = wv*2+j)
        ull L[2], Hh[2];
        const ull* hp = (const ull*)hfrag + ((long)(t - 1) * HB_STEP) / 4;
        if (t > 0 && pollme) {
            #pragma unroll
            for (int j = 0; j < 2; ++j) {
                const ull* p = hp + (((long)bt * 16 + (wv * 2 + j)) * 64 + lane) * 2;
                L[j]  = ald(p);
                Hh[j] = ald(p + 1);
            }
        }

        // 2) x B-frags + x-GEMM: h-independent, overlaps the polls' round trip
        const short* xr = xfrag + (long)t * XF_STEP;
        bf16x8 xf[8];
        #pragma unroll
        for (int kc = 0; kc < 8; ++kc)
            xf[kc] = *(const bf16x8*)(xr + ((long)(bt * 8 + kc) * 64 + lane) * 8);

        f32x4 a0 = (f32x4){b0[0], b0[1], b0[2], b0[3]};
        f32x4 a1 = (f32x4){b1[0], b1[1], b1[2], b1[3]};
        #pragma unroll
        for (int kc = 0; kc < 8; ++kc) {
            a0 = __builtin_amdgcn_mfma_f32_16x16x32_bf16(a_w[0][kc], xf[kc], a0, 0, 0, 0);
            a1 = __builtin_amdgcn_mfma_f32_16x16x32_bf16(a_w[1][kc], xf[kc], a1, 0, 0, 0);
        }

        if (t > 0 && pollme) {
            // 3) batched freshness spin (~1 RT/sweep), r7-proven mechanics
            unsigned stale = 0x3u;
            for (int g = 0; g < (1 << 20); ++g) {
                unsigned ns = 0;
                #pragma unroll
                for (int j = 0; j < 2; ++j)
                    if ((stale >> j) & 1u)
                        if (!__all(((L[j] | Hh[j]) & SGN) == 0)) ns |= (1u << j);
                stale = ns;                 // wave-uniform (from __all)
                if (!stale) break;
                #pragma unroll
                for (int j = 0; j < 2; ++j)
                    if ((stale >> j) & 1u) {
                        const ull* p = hp + (((long)bt * 16 + (wv * 2 + j)) * 64 + lane) * 2;
                        L[j]  = ald(p);
                        Hh[j] = ald(p + 1);
                    }
            }
            // 4) stage polled frags into LDS (self frags arrive via publish path)
            #pragma unroll
            for (int j = 0; j < 2; ++j) {
                ullx2 u; u[0] = L[j]; u[1] = Hh[j];
                *(ullx2*)(&lds[cb][wv * 2 + j][lane][0]) = u;
            }
        }
        __syncthreads();

        // 5) h-GEMM (K=512) from LDS, fused a0/a1, fixed kc order (determinism)
        if (t > 0) {
            #pragma unroll
            for (int kc = 0; kc < 16; ++kc) {
                bf16x8 hf = *(const bf16x8*)(&lds[cb][kc][lane][0]);
                a0 = __builtin_amdgcn_mfma_f32_16x16x32_bf16(a_u[0][kc], hf, a0, 0, 0, 0);
                a1 = __builtin_amdgcn_mfma_f32_16x16x32_bf16(a_u[1][kc], hf, a1, 0, 0, 0);
            }
        }

        // 6) gates: lane group g4 owns gate g4; shuffle so every lane gets
        //    (i,f,g,o) for its (q, batch col c16) of both j-blocks.
        float hv[8];
        #pragma unroll
        for (int blk = 0; blk < 2; ++blk) {
            #pragma unroll
            for (int q = 0; q < 4; ++q) {
                float z = blk ? a1[q] : a0[q];
                float a = (g4 == 2) ? fmaxf(z, 0.f)               // candidate: relu
                                    : 1.f / (1.f + __expf(-z));   // i,f,o: sigmoid
                float ai = __shfl(a, c16,      64);
                float af = __shfl(a, c16 + 16, 64);
                float ag = __shfl(a, c16 + 32, 64);
                float ao = __shfl(a, c16 + 48, 64);
                float c_ = af * cst[blk*4+q] + ai * ag;
                cst[blk*4+q] = c_;
                hv[blk*4+q] = ao * fmaxf(c_, 0.f);
            }
        }

        // 7) publish h(t): L3 (for the other 7 WGs) + own LDS (next step).
        //    The WG's 8 waves cover its 2 frags completely.
        if (t < T_ - 1) {
            if (g4 == 0) {
                ull p0 = (ull)f2bf(hv[0]) | ((ull)f2bf(hv[1])<<16)
                       | ((ull)f2bf(hv[2])<<32) | ((ull)f2bf(hv[3])<<48);
                ull p1 = (ull)f2bf(hv[4]) | ((ull)f2bf(hv[5])<<16)
                       | ((ull)f2bf(hv[6])<<32) | ((ull)f2bf(hv[7])<<48);
                ull* d = pub0 + (long)t * (HB_STEP / 4);
                ast(d, p0); ast(d + 1, p1);
                ullx2 u; u[0] = p0; u[1] = p1;
                *(ullx2*)(&lds[(t + 1) & 1][kcw][(wv & 3) * 16 + c16][0]) = u;
            }
        } else {
            if (g4 == 0) {
                *(float4*)(hfin + ((long)bt * 16 + c16) * H_ + hs * 8)
                    = make_float4(hv[0], hv[1], hv[2], hv[3]);
                *(float4*)(hfin + ((long)bt * 16 + c16) * H_ + hs * 8 + 4)
                    = make_float4(hv[4], hv[5], hv[6], hv[7]);
            }
        }
    }
}

// ---------------- C: dense head + softmax ----------------
__global__ __launch_bounds__(256) void k_head(const float* __restrict__ hfin,
                                              const float* __restrict__ W2,
                                              const float* __restrict__ b2,
                                              const float* __restrict__ W3,
                                              const float* __restrict__ b3,
                                              float* __restrict__ out) {
    __shared__ float hs[H_];
    __shared__ float ys[U1_];
    __shared__ float ps[4][U2_];
    const int b = blockIdx.x, tid = threadIdx.x;
    if (tid < 128) *(float4*)(hs + tid * 4) = *(const float4*)(hfin + (long)b * H_ + tid * 4);
    __syncthreads();
    float acc = b2[tid];
    #pragma unroll 8
    for (int k = 0; k < H_; ++k) acc += hs[k] * W2[(long)k * U1_ + tid];
    ys[tid] = fmaxf(acc, 0.f);
    __syncthreads();
    const int u2 = tid & 63, part = tid >> 6;
    float p = 0.f;
    #pragma unroll 8
    for (int k = part * 64; k < part * 64 + 64; ++k) p += ys[k] * W3[(long)k * U2_ + u2];
    ps[part][u2] = p;
    __syncthreads();
    if (tid < 64) {
        float lg = b3[tid] + ps[0][tid] + ps[1][tid] + ps[2][tid] + ps[3][tid];
        float m = lg;
        #pragma unroll
        for (int off = 32; off >= 1; off >>= 1) m = fmaxf(m, __shfl_xor(m, off, 64));
        float e = __expf(lg - m);
        float s = e;
        #pragma unroll
        for (int off = 32; off >= 1; off >>= 1) s += __shfl_xor(s, off, 64);
        out[(long)b * U2_ + tid] = e / s;
    }
}

extern "C" void kernel_launch(void* const* d_in, const int* in_sizes, int n_in,
                              void* d_out, int out_size, void* d_ws, size_t ws_size,
                              hipStream_t stream) {
    const int*   inp = (const int*)d_in[0];
    const float* emb = (const float*)d_in[1];
    const float* W   = (const float*)d_in[2];
    const float* U   = (const float*)d_in[3];
    const float* bb  = (const float*)d_in[4];
    const float* W2  = (const float*)d_in[5];
    const float* b2  = (const float*)d_in[6];
    const float* W3  = (const float*)d_in[7];
    const float* b3  = (const float*)d_in[8];

    char* ws = (char*)d_ws;
    const long HB_BYTES = (long)(T_ - 1) * HB_STEP * 2;      // 33,292,288
    short* hfrag = (short*)ws;                                // [0, 31.75MB)
    short* xfrag = (short*)(ws + HB_BYTES);                   // 16 MiB
    short* wpk   = (short*)(ws + HB_BYTES + 16777216);        // 3 MiB
    float* hfin  = (float*)(ws + HB_BYTES + 16777216 + 3145728); // 512 KiB

    // re-poison the write-once h buffer every call (determinism across replays)
    hipMemsetAsync(hfrag, 0xAA, HB_BYTES, stream);
    k_prep<<<32, 256, 0, stream>>>(U, W, wpk);
    k_gather<<<256, 256, 0, stream>>>(inp, emb, xfrag);
    k_lstm<<<128, 512, 0, stream>>>(bb, wpk, xfrag, hfrag, hfin);
    k_head<<<B_, 256, 0, stream>>>(hfin, W2, b2, W3, b3, (float*)d_out);
}

// Round 12
// 507.620 us; speedup vs baseline: 1.3101x; 1.3101x over previous
//
#include <hip/hip_runtime.h>
#include <hip/hip_bf16.h>
#include <stdint.h>

#define B_  256
#define T_  128
#define E_  256
#define H_  512
#define G4  2048
#define U1_ 256
#define U2_ 64

#define HB_STEP   (16 * 16 * 64 * 8)   // shorts per h step-buffer (256 KB)
#define XF_STEP   (16 * 8 * 64 * 8)    // shorts per x step (128 KB)
#define SGN 0x8000800080008000ULL

typedef __attribute__((ext_vector_type(8))) short bf16x8;
typedef __attribute__((ext_vector_type(4))) float f32x4;
typedef __attribute__((ext_vector_type(2))) unsigned long long ullx2;
typedef unsigned long long ull;

static __device__ __forceinline__ unsigned short f2bf(float f) {
    unsigned u = __float_as_uint(f);
    unsigned r = (u + 0x7FFFu + ((u >> 16) & 1u)) >> 16;   // RNE
    return (unsigned short)r;
}
static __device__ __forceinline__ ull ald(const ull* p) {
    return __hip_atomic_load(p, __ATOMIC_RELAXED, __HIP_MEMORY_SCOPE_AGENT);
}
static __device__ __forceinline__ void ast(ull* p, ull v) {
    __hip_atomic_store(p, v, __ATOMIC_RELAXED, __HIP_MEMORY_SCOPE_AGENT);
}

// ---------- A0: pack U,W (f32 row-major) into bf16 MFMA A-frag layout ----------
__global__ __launch_bounds__(256) void k_prep(const float* __restrict__ U,
                                              const float* __restrict__ W,
                                              short* __restrict__ wpk) {
    __shared__ float ld[32][64];
    const int bj = blockIdx.x;          // 0..31: (gate, 64-wide j window)
    const int g  = bj >> 3;
    const int l0 = (bj & 7) * 64;
    const int t  = threadIdx.x;
    const int p   = t >> 4;             // 0..15 -> (hs_local, blk)
    const int hsl = p >> 1, blk = p & 1;
    const int ci  = t & 3;
    const int g4w = (t >> 2) & 3;
    const int hs  = (l0 >> 3) + hsl;
    const int c16 = g * 4 + ci;
    const int jloc = hsl * 8 + blk * 4 + ci;
    for (int kc = 0; kc < 24; ++kc) {
        const float* src = (kc < 16) ? (U + (long)(kc * 32) * G4)
                                     : (W + (long)((kc - 16) * 32) * G4);
        #pragma unroll
        for (int r = 0; r < 8; ++r) {
            int row = r * 4 + (t >> 6);
            ld[row][t & 63] = src[(long)row * G4 + g * 512 + l0 + (t & 63)];
        }
        __syncthreads();
        bf16x8 o;
        #pragma unroll
        for (int e = 0; e < 8; ++e) o[e] = (short)f2bf(ld[g4w * 8 + e][jloc]);
        *(bf16x8*)(wpk + (((long)(hs * 2 + blk) * 24 + kc) * 64 + (g4w * 16 + c16)) * 8) = o;
        __syncthreads();
    }
}

// ---------- A1: gather embeddings -> x in MFMA B-frag layout (bf16) ----------
__global__ __launch_bounds__(256) void k_gather(const int* __restrict__ inp,
                                                const float* __restrict__ emb,
                                                short* __restrict__ xfrag) {
    const int tid  = threadIdx.x;
    const int wv   = tid >> 6;
    const int lane = tid & 63;
    const int c16  = lane & 15;
    const int g4   = lane >> 4;
    for (int it = 0; it < 16; ++it) {
        int task  = (it * 256 + blockIdx.x) * 4 + wv;   // t*128 + btile*8 + kc
        int kc    = task & 7;
        int btile = (task >> 3) & 15;
        int t     = task >> 7;
        int b     = btile * 16 + c16;
        int idx   = inp[b * T_ + t];
        const float* src = emb + (long)idx * E_ + kc * 32 + g4 * 8;
        float4 v0 = *(const float4*)src;
        float4 v1 = *(const float4*)(src + 4);
        bf16x8 o;
        o[0]=(short)f2bf(v0.x); o[1]=(short)f2bf(v0.y); o[2]=(short)f2bf(v0.z); o[3]=(short)f2bf(v0.w);
        o[4]=(short)f2bf(v1.x); o[5]=(short)f2bf(v1.y); o[6]=(short)f2bf(v1.z); o[7]=(short)f2bf(v1.w);
        *(bf16x8*)(xfrag + ((long)((t * 16 + btile) * 8 + kc) * 64 + lane) * 8) = o;
    }
}

// ---------------- B: persistent recurrent kernel, pure dataflow ----------------
// r7-proven base: WG = (bt, hsg), 16 WGs/pipeline, relaxed agent 8B comms,
// data-as-flag on bf16 sign bits, write-once 0xAA-poisoned T-deep buffer,
// LDS share of polled frags. Round-11 latency trims:
//   (1) x loads issued BEFORE polls (FIFO vmcnt: x-MFMA waits vmcnt(8), does
//       not drain polls);
//   (2) 2-deep ping-pong polling (check older sweep while newer in flight);
//   (3) pre-barrier MFMAs of own polled frags from registers (static kc
//       indices via uniform guards), only 24 MFMAs post-barrier;
//   (4) split publish: p0 stored right after blk0 gates, p1 after blk1.
__global__ __launch_bounds__(256, 1) void k_lstm(
    const float* __restrict__ bias,   // [G4]
    const short* __restrict__ wpk,    // packed A-frags
    const short* __restrict__ xfrag,  // [T_][16][8][64][8] bf16
    short* hfrag,                     // [T_-1][16][16][64][8] bf16, poisoned
    float* hfin)                      // [B_][H_] f32
{
    __shared__ short lds[2][16][64][8];   // 2 x 16 KB h-frag buffers
    const int tid  = threadIdx.x;
    const int wid  = blockIdx.x;      // 0..255
    const int bt   = wid >> 4;        // batch tile 0..15 (16 rows)
    const int hsg  = wid & 15;        // hidden-slice group; owns frag kc=hsg
    const int lane = tid & 63;
    const int wv   = tid >> 6;
    const int hs   = hsg * 4 + wv;    // this wave's hidden slice (8 units)
    const int c16  = lane & 15;
    const int g4   = lane >> 4;
    const int selfj = ((hsg >> 2) == wv) ? (hsg & 3) : -1;   // wave-uniform

    // Persistent A-frags, coalesced load from wpk (2 j-blocks x (16 U + 8 W))
    bf16x8 a_u[2][16], a_w[2][8];
    #pragma unroll
    for (int blk = 0; blk < 2; ++blk) {
        #pragma unroll
        for (int kc = 0; kc < 16; ++kc)
            a_u[blk][kc] = *(const bf16x8*)(wpk + (((long)(hs*2+blk)*24 + kc)*64 + lane)*8);
        #pragma unroll
        for (int kc = 0; kc < 8; ++kc)
            a_w[blk][kc] = *(const bf16x8*)(wpk + (((long)(hs*2+blk)*24 + 16 + kc)*64 + lane)*8);
    }
    float b0[4], b1[4];
    #pragma unroll
    for (int q = 0; q < 4; ++q) {
        b0[q] = bias[g4 * H_ + hs * 8 + q];
        b1[q] = bias[g4 * H_ + hs * 8 + 4 + q];
    }
    float cst[8];
    #pragma unroll
    for (int i = 0; i < 8; ++i) cst[i] = 0.f;

    // publish slot: frag (bt, hsg), lane slot wv*16 + c16
    ull* const pub0 = (ull*)hfrag + (((long)bt * 16 + hsg) * 64 + wv * 16 + c16) * 2;

    for (int t = 0; t < T_; ++t) {
        const int cb = t & 1;
        const ull* hp = (const ull*)hfrag + ((long)(t - 1) * HB_STEP) / 4;

        // (1) x B-frag loads FIRST in the vmcnt FIFO
        const short* xr = xfrag + (long)t * XF_STEP;
        bf16x8 xf[8];
        #pragma unroll
        for (int kc = 0; kc < 8; ++kc)
            xf[kc] = *(const bf16x8*)(xr + ((long)(bt * 8 + kc) * 64 + lane) * 8);

        // initial poll sweep A (compiler-visible relaxed atomics)
        ull LA[4], HA[4], LB[4], HB[4], L[4], Hh[4];
        if (t > 0) {
            #pragma unroll
            for (int j = 0; j < 4; ++j) if (j != selfj) {
                const ull* p = hp + (((long)bt * 16 + (wv * 4 + j)) * 64 + lane) * 2;
                LA[j] = ald(p); HA[j] = ald(p + 1);
            }
        }

        // x-GEMM: waits only the x loads (earlier in FIFO than polls)
        f32x4 a0 = (f32x4){b0[0], b0[1], b0[2], b0[3]};
        f32x4 a1 = (f32x4){b1[0], b1[1], b1[2], b1[3]};
        #pragma unroll
        for (int kc = 0; kc < 8; ++kc) {
            a0 = __builtin_amdgcn_mfma_f32_16x16x32_bf16(a_w[0][kc], xf[kc], a0, 0, 0, 0);
            a1 = __builtin_amdgcn_mfma_f32_16x16x32_bf16(a_w[1][kc], xf[kc], a1, 0, 0, 0);
        }

        if (t > 0) {
            unsigned stale = 0xFu & ~((selfj >= 0) ? (1u << selfj) : 0u);
            // check initial A sweep
            {
                unsigned ns = 0;
                #pragma unroll
                for (int j = 0; j < 4; ++j) if ((stale >> j) & 1u) {
                    if (__all(((LA[j] | HA[j]) & SGN) == 0)) { L[j] = LA[j]; Hh[j] = HA[j]; }
                    else ns |= (1u << j);
                }
                stale = ns;
            }
            if (stale) {
                // (2) ping-pong: always one sweep in flight while checking the older
                #pragma unroll
                for (int j = 0; j < 4; ++j) if ((stale >> j) & 1u) {
                    const ull* p = hp + (((long)bt * 16 + (wv * 4 + j)) * 64 + lane) * 2;
                    LB[j] = ald(p); HB[j] = ald(p + 1);
                }
                for (int g = 0; g < (1 << 18); ++g) {
                    #pragma unroll
                    for (int j = 0; j < 4; ++j) if ((stale >> j) & 1u) {
                        const ull* p = hp + (((long)bt * 16 + (wv * 4 + j)) * 64 + lane) * 2;
                        LA[j] = ald(p); HA[j] = ald(p + 1);
                    }
                    unsigned ns = 0;
                    #pragma unroll
                    for (int j = 0; j < 4; ++j) if ((stale >> j) & 1u) {
                        if (__all(((LB[j] | HB[j]) & SGN) == 0)) { L[j] = LB[j]; Hh[j] = HB[j]; }
                        else ns |= (1u << j);
                    }
                    stale = ns;
                    if (!stale) break;
                    #pragma unroll
                    for (int j = 0; j < 4; ++j) if ((stale >> j) & 1u) {
                        const ull* p = hp + (((long)bt * 16 + (wv * 4 + j)) * 64 + lane) * 2;
                        LB[j] = ald(p); HB[j] = ald(p + 1);
                    }
                    ns = 0;
                    #pragma unroll
                    for (int j = 0; j < 4; ++j) if ((stale >> j) & 1u) {
                        if (__all(((LA[j] | HA[j]) & SGN) == 0)) { L[j] = LA[j]; Hh[j] = HA[j]; }
                        else ns |= (1u << j);
                    }
                    stale = ns;
                    if (!stale) break;
                }
            }
            // stage polled frags to LDS for the other waves
            #pragma unroll
            for (int j = 0; j < 4; ++j) if (j != selfj) {
                ullx2 u; u[0] = L[j]; u[1] = Hh[j];
                *(ullx2*)(&lds[cb][wv * 4 + j][lane][0]) = u;
            }
            // (3) pre-barrier MFMAs of own polled frags (static kc, uniform guard)
            #pragma unroll
            for (int kc = 0; kc < 16; ++kc) {
                if ((kc >> 2) != wv || (kc & 3) == selfj) continue;
                ullx2 u; u[0] = L[kc & 3]; u[1] = Hh[kc & 3];
                bf16x8 hf = __builtin_bit_cast(bf16x8, u);
                a0 = __builtin_amdgcn_mfma_f32_16x16x32_bf16(a_u[0][kc], hf, a0, 0, 0, 0);
                a1 = __builtin_amdgcn_mfma_f32_16x16x32_bf16(a_u[1][kc], hf, a1, 0, 0, 0);
            }
        }
        __syncthreads();

        // remaining h-GEMM from LDS (fixed kc order; own polled kc already done)
        if (t > 0) {
            #pragma unroll
            for (int kc = 0; kc < 16; ++kc) {
                if ((kc >> 2) == wv && (kc & 3) != selfj) continue;
                bf16x8 hf = *(const bf16x8*)(&lds[cb][kc][lane][0]);
                a0 = __builtin_amdgcn_mfma_f32_16x16x32_bf16(a_u[0][kc], hf, a0, 0, 0, 0);
                a1 = __builtin_amdgcn_mfma_f32_16x16x32_bf16(a_u[1][kc], hf, a1, 0, 0, 0);
            }
        }

        // gates + (4) split publish: p0 right after blk0 gates
        ull* const d = pub0 + (long)t * (HB_STEP / 4);
        float hv[8];
        #pragma unroll
        for (int q = 0; q < 4; ++q) {
            float z = a0[q];
            float a = (g4 == 2) ? fmaxf(z, 0.f) : 1.f / (1.f + __expf(-z));
            float ai = __shfl(a, c16,      64);
            float af = __shfl(a, c16 + 16, 64);
            float ag = __shfl(a, c16 + 32, 64);
            float ao = __shfl(a, c16 + 48, 64);
            float c_ = af * cst[q] + ai * ag;
            cst[q] = c_;
            hv[q] = ao * fmaxf(c_, 0.f);
        }
        ull p0 = (ull)f2bf(hv[0]) | ((ull)f2bf(hv[1])<<16)
               | ((ull)f2bf(hv[2])<<32) | ((ull)f2bf(hv[3])<<48);
        if (t < T_ - 1 && g4 == 0) ast(d, p0);
        #pragma unroll
        for (int q = 0; q < 4; ++q) {
            float z = a1[q];
            float a = (g4 == 2) ? fmaxf(z, 0.f) : 1.f / (1.f + __expf(-z));
            float ai = __shfl(a, c16,      64);
            float af = __shfl(a, c16 + 16, 64);
            float ag = __shfl(a, c16 + 32, 64);
            float ao = __shfl(a, c16 + 48, 64);
            float c_ = af * cst[4 + q] + ai * ag;
            cst[4 + q] = c_;
            hv[4 + q] = ao * fmaxf(c_, 0.f);
        }
        ull p1 = (ull)f2bf(hv[4]) | ((ull)f2bf(hv[5])<<16)
               | ((ull)f2bf(hv[6])<<32) | ((ull)f2bf(hv[7])<<48);

        if (t < T_ - 1) {
            if (g4 == 0) {
                ast(d + 1, p1);
                ullx2 u; u[0] = p0; u[1] = p1;
                *(ullx2*)(&lds[(t + 1) & 1][hsg][wv * 16 + c16][0]) = u;
            }
        } else {
            if (g4 == 0) {
                *(float4*)(hfin + ((long)bt * 16 + c16) * H_ + hs * 8)
                    = make_float4(hv[0], hv[1], hv[2], hv[3]);
                *(float4*)(hfin + ((long)bt * 16 + c16) * H_ + hs * 8 + 4)
                    = make_float4(hv[4], hv[5], hv[6], hv[7]);
            }
        }
    }
}

// ---------------- C: dense head + softmax ----------------
__global__ __launch_bounds__(256) void k_head(const float* __restrict__ hfin,
                                              const float* __restrict__ W2,
                                              const float* __restrict__ b2,
                                              const float* __restrict__ W3,
                                              const float* __restrict__ b3,
                                              float* __restrict__ out) {
    __shared__ float hs[H_];
    __shared__ float ys[U1_];
    __shared__ float ps[4][U2_];
    const int b = blockIdx.x, tid = threadIdx.x;
    if (tid < 128) *(float4*)(hs + tid * 4) = *(const float4*)(hfin + (long)b * H_ + tid * 4);
    __syncthreads();
    float acc = b2[tid];
    #pragma unroll 8
    for (int k = 0; k < H_; ++k) acc += hs[k] * W2[(long)k * U1_ + tid];
    ys[tid] = fmaxf(acc, 0.f);
    __syncthreads();
    const int u2 = tid & 63, part = tid >> 6;
    float p = 0.f;
    #pragma unroll 8
    for (int k = part * 64; k < part * 64 + 64; ++k) p += ys[k] * W3[(long)k * U2_ + u2];
    ps[part][u2] = p;
    __syncthreads();
    if (tid < 64) {
        float lg = b3[tid] + ps[0][tid] + ps[1][tid] + ps[2][tid] + ps[3][tid];
        float m = lg;
        #pragma unroll
        for (int off = 32; off >= 1; off >>= 1) m = fmaxf(m, __shfl_xor(m, off, 64));
        float e = __expf(lg - m);
        float s = e;
        #pragma unroll
        for (int off = 32; off >= 1; off >>= 1) s += __shfl_xor(s, off, 64);
        out[(long)b * U2_ + tid] = e / s;
    }
}

extern "C" void kernel_launch(void* const* d_in, const int* in_sizes, int n_in,
                              void* d_out, int out_size, void* d_ws, size_t ws_size,
                              hipStream_t stream) {
    const int*   inp = (const int*)d_in[0];
    const float* emb = (const float*)d_in[1];
    const float* W   = (const float*)d_in[2];
    const float* U   = (const float*)d_in[3];
    const float* bb  = (const float*)d_in[4];
    const float* W2  = (const float*)d_in[5];
    const float* b2  = (const float*)d_in[6];
    const float* W3  = (const float*)d_in[7];
    const float* b3  = (const float*)d_in[8];

    char* ws = (char*)d_ws;
    const long HB_BYTES = (long)(T_ - 1) * HB_STEP * 2;      // 33,292,288
    short* hfrag = (short*)ws;                                // [0, 31.75MB)
    short* xfrag = (short*)(ws + HB_BYTES);                   // 16 MiB
    short* wpk   = (short*)(ws + HB_BYTES + 16777216);        // 3 MiB
    float* hfin  = (float*)(ws + HB_BYTES + 16777216 + 3145728); // 512 KiB

    // re-poison the write-once h buffer every call (determinism across replays)
    hipMemsetAsync(hfrag, 0xAA, HB_BYTES, stream);
    k_prep<<<32, 256, 0, stream>>>(U, W, wpk);
    k_gather<<<256, 256, 0, stream>>>(inp, emb, xfrag);
    k_lstm<<<256, 256, 0, stream>>>(bb, wpk, xfrag, hfrag, hfin);
    k_head<<<B_, 256, 0, stream>>>(hfin, W2, b2, W3, b3, (float*)d_out);
}